// Round 6
// baseline (212.866 us; speedup 1.0000x reference)
//
#include <hip/hip_runtime.h>
#include <hip/hip_fp16.h>

// Problem constants
#define HDIM 256
#define WDIM 1216
#define HWC  (HDIM*WDIM)     // 311296
#define NPTS 40000
#define KNN  9
#define PIXR 256             // index range of pixel coords (0..255)
#define EPSF 1e-5f

typedef __attribute__((ext_vector_type(8))) short bf16x8;
typedef __attribute__((ext_vector_type(4))) float f32x4;

static __device__ __forceinline__ unsigned short f2bf(float f) {
    unsigned int u = __float_as_uint(f);
    u += 0x7FFFu + ((u >> 16) & 1u);     // round-nearest-even
    return (unsigned short)(u >> 16);
}

static __device__ __forceinline__ float h2f(unsigned short u) {
    __half h = __builtin_bit_cast(__half, u);
    return __half2float(h);
}

// ---------------------------------------------------------------------------
// Kernel 1: prep — feature transpose to fp16 [pix][chan] (1024 blocks) +
// workspace init side-jobs (winner=-1, sums=0). Stream order guarantees init
// before point_k. R14: feat_t is fp16 — halves prep write traffic (16.7->8.4
// MB), halves point_k's gather payload and image footprint (better per-XCD
// L2 retention). fp16 (10-bit mantissa) adds ~1/8 of the existing bf16-msg
// rounding error -> absmax unchanged.
// ---------------------------------------------------------------------------
__global__ __launch_bounds__(256) void prep_k(const float* __restrict__ feat,
                                              unsigned short* __restrict__ feat_t,
                                              int* __restrict__ winner,
                                              float* __restrict__ sums) {
    __shared__ float tile[64][65];
    const int iy   = blockIdx.x >> 2;
    const int ixb  = (blockIdx.x & 3) * 64;
    const int lane = threadIdx.x & 63;
    const int w    = threadIdx.x >> 6;

    const int tid = blockIdx.x * 256 + threadIdx.x;
    if (tid < PIXR * PIXR) winner[tid] = -1;
    if (tid < 128) sums[tid] = 0.f;

#pragma unroll
    for (int r = 0; r < 16; ++r) {
        int cc = w * 16 + r;
        tile[cc][lane] = feat[cc * HWC + iy * WDIM + ixb + lane];   // 256B coalesced
    }
    __syncthreads();
#pragma unroll
    for (int r = 0; r < 16; ++r) {
        int ix = w * 16 + r;
        unsigned short hv = __builtin_bit_cast(unsigned short,
                                               __float2half_rn(tile[lane][ix]));
        feat_t[(iy * PIXR + ixb + ix) * 64 + lane] = hv;  // 128B/wave coalesced
    }
}

// ---------------------------------------------------------------------------
// Kernel 2: MFMA point kernel. R14 = R13 structure (proven: 2-deep gather
// pipeline, (512,2) = 4-waves/EU floor -> 128-VGPR budget, shfl quad-reduce,
// row-id npx, 39.9KB LDS) + fp16 feat_t gathers:
//   * each lane: ushort4 (8B) per neighbor instead of float4 (16B) — halves
//     gather bytes (92->46MB) and L2-miss refetch (R4 FETCH 40.7MB, ~16MB
//     of which was gather re-miss on the 16.7MB image; 8.4MB image retains
//     much better in the 4MB per-XCD L2s).
//   * v_cvt_f32_f16 at consume (16/ISSUE) — VALU 22% busy, absorbed.
// launch_bounds 2nd-arg decode (R2/R3): waves/EU floor = 2*N for 512-thr
// blocks; (512,6) caused a 40-VGPR spill disaster. (512,2) is proven clean.
// ---------------------------------------------------------------------------
__global__ __launch_bounds__(512, 2) void point_k(
    const unsigned short* __restrict__ feat_t, // [256*256, 64] fp16
    const float* __restrict__ diff,     // [N, 9, 3]
    const int*   __restrict__ nnpix,    // [N, 9, 2]
    const int*   __restrict__ pix,      // [N, 2]
    const float* __restrict__ W1,       // [3, 32]
    const float* __restrict__ b1,       // [32]
    const float* __restrict__ W2,       // [32, 64]
    const float* __restrict__ b2,       // [64]
    const float* __restrict__ conv_w,   // [64, 64] (out, in)
    const float* __restrict__ conv_b,   // [64]
    int*   __restrict__ winner,         // [256*256]
    float* __restrict__ y_buf,          // [N, 64]
    float* __restrict__ sums)           // [128]
{
    __shared__ float dstage[8][224];          // diff (216 used); reused for BN staging
    __shared__ int   npx[8][96];              // row-ids, 12/point (9 used), per wave
    __shared__ unsigned int hl[8][2][320];    // hmid, double-buffered, 80B row stride
    __shared__ unsigned short msgst[8][576];  // msg [8 pts][72 u16] per wave
    // total: 7168 + 3072 + 20480 + 9216 = 39936 B

    const int l   = threadIdx.x & 63;
    const int w   = __builtin_amdgcn_readfirstlane(threadIdx.x >> 6);
    const int q   = l >> 4;
    const int col = l & 15;
    const int nbase = blockIdx.x * 64 + w * 8;    // wave's 8 points

    // winner side-job: one thread per point of this block (64 points)
    if (threadIdx.x < 64) {
        int n = blockIdx.x * 64 + threadIdx.x;
        int px = pix[2 * n];
        int py = pix[2 * n + 1];
        atomicMax(&winner[py * PIXR + px], n);
    }

    // ---- persistent fragments for the g-loop ----
    // W2 B-frag under the channel remap: B[j = 8q+t][n=col] holds c = 4*col+m.
    bf16x8 bw2[4];
#pragma unroll
    for (int t = 0; t < 8; ++t) {
        float4 v = ((const float4*)W2)[(q * 8 + t) * 16 + col];
        bw2[0][t] = (short)f2bf(v.x);
        bw2[1][t] = (short)f2bf(v.y);
        bw2[2][t] = (short)f2bf(v.z);
        bw2[3][t] = (short)f2bf(v.w);
    }
    float b2m[4];
    {
        float4 bv = ((const float4*)b2)[col];
        b2m[0] = bv.x; b2m[1] = bv.y; b2m[2] = bv.z; b2m[3] = bv.w;
    }

    // W1 columns for phase A (j0 = 2*col, j0+1)
    const int j0 = 2 * col;
    const float wa0 = W1[j0],     wa1 = W1[32 + j0],     wa2 = W1[64 + j0],     ba = b1[j0];
    const float wb0 = W1[j0 + 1], wb1 = W1[32 + j0 + 1], wb2 = W1[64 + j0 + 1], bb = b1[j0 + 1];

    // preload diff (216 f32) for the wave's 8 points
#pragma unroll
    for (int t = 0; t < 4; ++t) { int idx = l + 64 * t; if (idx < 216) dstage[w][idx] = diff[nbase * 27 + idx]; }
    // preload nnpix as precomputed row-ids, 12-padded per point (96 ints)
#pragma unroll
    for (int t = 0; t < 2; ++t) {
        int idx = l + 64 * t;
        if (idx < 96) {
            int point = idx / 12;
            int k     = idx - point * 12;
            int rid = 0;
            if (k < 9) {
                int2 pp = *(const int2*)(nnpix + (nbase + point) * 18 + 2 * k);
                rid = pp.y * PIXR + pp.x;
            }
            npx[w][idx] = rid;
        }
    }

    // zero hmid pad rows 9..15 in BOTH buffers
    for (int z = 180 + l; z < 320; z += 64) { hl[w][0][z] = 0; hl[w][1][z] = 0; }

    // gather pipeline buffers — named, statically indexed only
    float fvc[4][4], fvn[4][4], fv2[4][4];   // [neighbor i][m], c = 4*col+m

// issue the 4 neighbor-row gathers for point gg into named buffer `buf`
// fp16: 8B ushort4 per (neighbor, lane), cvt to f32 at fill
#define ISSUE_INTO(buf, gg)                                                     \
    {                                                                           \
        int4 r4 = *(const int4*)&npx[w][(gg) * 12 + q * 4];                     \
        int rid[4] = {r4.x, r4.y, r4.z, r4.w};                                  \
        _Pragma("unroll")                                                       \
        for (int i = 0; i < 4; ++i) {                                           \
            int k = q * 4 + i;                                                  \
            buf[i][0] = 0.f; buf[i][1] = 0.f; buf[i][2] = 0.f; buf[i][3] = 0.f; \
            if (k < 9) {                                                        \
                ushort4 u4 = *(const ushort4*)(feat_t + rid[i] * 64 + 4 * col); \
                buf[i][0] = h2f(u4.x); buf[i][1] = h2f(u4.y);                   \
                buf[i][2] = h2f(u4.z); buf[i][3] = h2f(u4.w);                   \
            }                                                                   \
        }                                                                       \
    }

// MLP layer 1 for point gg -> hl[(gg)&1]
#define PHASE_A(gg)                                                             \
    {                                                                           \
        unsigned int* hln = hl[w][(gg) & 1];                                    \
        _Pragma("unroll")                                                       \
        for (int i2 = 0; i2 < 3; ++i2) {                                        \
            int k2 = q + 4 * i2;                                                \
            if (k2 < 9) {                                                       \
                float d0 = dstage[w][(gg) * 27 + k2 * 3];                       \
                float d1 = dstage[w][(gg) * 27 + k2 * 3 + 1];                   \
                float d2 = dstage[w][(gg) * 27 + k2 * 3 + 2];                   \
                float h0 = fmaxf(fmaf(d0, wa0, fmaf(d1, wa1, fmaf(d2, wa2, ba))), 0.f); \
                float h1 = fmaxf(fmaf(d0, wb0, fmaf(d1, wb1, fmaf(d2, wb2, bb))), 0.f); \
                hln[k2 * 20 + col] = (unsigned int)f2bf(h0) | ((unsigned int)f2bf(h1) << 16); \
            }                                                                   \
        }                                                                       \
    }

    // zero-init fv2 (read by rotation before first conditional issue paths)
#pragma unroll
    for (int i = 0; i < 4; ++i)
#pragma unroll
        for (int m = 0; m < 4; ++m) fv2[i][m] = 0.f;

    // ---- pipeline prologue: gathers for g=0 and g=1, phase A for g=0 ----
    ISSUE_INTO(fvc, 0);
    ISSUE_INTO(fvn, 1);
    PHASE_A(0);

    for (int g = 0; g < 8; ++g) {
        // --- issue gathers 2 ahead, phase A 1 ahead ---
        if (g < 6) ISSUE_INTO(fv2, g + 2);
        if (g < 7) PHASE_A(g + 1);           // writes hl[(g+1)&1], != hl[g&1]

        // --- phase B(g): wts via MFMA, weighted neighbor sum ---
        // quad partials reduced with __shfl_xor (wave-private, register-only);
        // quad 0 writes the packed bf16 msg line (8B) — no LDS round-trip.
        bf16x8 a;
        {
            uint4 av = *(const uint4*)((const char*)hl[w][g & 1] + col * 80 + q * 16);
            a = __builtin_bit_cast(bf16x8, av);
        }
        float pm[4];
#pragma unroll
        for (int m = 0; m < 4; ++m) {
            f32x4 acc = {b2m[m], b2m[m], b2m[m], b2m[m]};
            acc = __builtin_amdgcn_mfma_f32_16x16x32_bf16(a, bw2[m], acc, 0, 0, 0);
            float p = 0.f;
#pragma unroll
            for (int i = 0; i < 4; ++i)
                p = fmaf(fmaxf(acc[i], 0.f), fvc[i][m], p);
            p += __shfl_xor(p, 16);
            p += __shfl_xor(p, 32);
            pm[m] = p;
        }
        if (q == 0) {
            ushort4 ms;
            ms.x = f2bf(pm[0]); ms.y = f2bf(pm[1]);
            ms.z = f2bf(pm[2]); ms.w = f2bf(pm[3]);
            *(ushort4*)(&msgst[w][g * 72 + 4 * col]) = ms;   // c = 4*col+m, 8B
        }

        // rotate pipeline registers: fvc <- fvn <- fv2
#pragma unroll
        for (int i = 0; i < 4; ++i)
#pragma unroll
            for (int m = 0; m < 4; ++m) { fvc[i][m] = fvn[i][m]; fvn[i][m] = fv2[i][m]; }
    }
#undef ISSUE_INTO
#undef PHASE_A

    // ---- phase C: batched 1x1 conv over the wave's 8 points ----
    // D rows 0..7 are the valid points (quads 0,1); rows 8..15 are discarded
    // duplicates (A-frag row col&7), so quads 2,3 skip stores/BN.
    bf16x8 bcv[4][2];
#pragma unroll
    for (int m = 0; m < 4; ++m)
#pragma unroll
        for (int h = 0; h < 2; ++h) {
            float4 v0 = ((const float4*)conv_w)[(col + 16 * m) * 16 + h * 8 + q * 2];
            float4 v1 = ((const float4*)conv_w)[(col + 16 * m) * 16 + h * 8 + q * 2 + 1];
            bcv[m][h][0] = (short)f2bf(v0.x); bcv[m][h][1] = (short)f2bf(v0.y);
            bcv[m][h][2] = (short)f2bf(v0.z); bcv[m][h][3] = (short)f2bf(v0.w);
            bcv[m][h][4] = (short)f2bf(v1.x); bcv[m][h][5] = (short)f2bf(v1.y);
            bcv[m][h][6] = (short)f2bf(v1.z); bcv[m][h][7] = (short)f2bf(v1.w);
        }
    float cbm[4];
#pragma unroll
    for (int m = 0; m < 4; ++m) cbm[m] = conv_b[col + 16 * m];

    float s1[4] = {0.f, 0.f, 0.f, 0.f}, s2[4] = {0.f, 0.f, 0.f, 0.f};

    bf16x8 am[2];
    const int crow = col & 7;
#pragma unroll
    for (int h = 0; h < 2; ++h) {
        uint4 av = *(const uint4*)((const char*)msgst[w] + crow * 144 + h * 64 + q * 16);
        am[h] = __builtin_bit_cast(bf16x8, av);
    }
#pragma unroll
    for (int m = 0; m < 4; ++m) {
        f32x4 acc = {cbm[m], cbm[m], cbm[m], cbm[m]};
        acc = __builtin_amdgcn_mfma_f32_16x16x32_bf16(am[0], bcv[m][0], acc, 0, 0, 0);
        acc = __builtin_amdgcn_mfma_f32_16x16x32_bf16(am[1], bcv[m][1], acc, 0, 0, 0);
        if (q < 2) {
#pragma unroll
            for (int i = 0; i < 4; ++i) {
                float y = acc[i];                    // row n_local = 4q+i, col c
                y_buf[(nbase + q * 4 + i) * 64 + col + 16 * m] = y;
                s1[m] += y;
                s2[m] = fmaf(y, y, s2[m]);
            }
        }
    }

    // ---- BN partials: cross-quad shfl reduce -> per-wave staging in dstage
    //      (dead after g-loop) -> one block-level reduction -> 128 atomics ----
#pragma unroll
    for (int m = 0; m < 4; ++m) {
        float a1 = s1[m], a2 = s2[m];
        a1 += __shfl_xor(a1, 16); a1 += __shfl_xor(a1, 32);
        a2 += __shfl_xor(a2, 16); a2 += __shfl_xor(a2, 32);
        if (q == 0) {
            dstage[w][col + 16 * m]      = a1;
            dstage[w][64 + col + 16 * m] = a2;
        }
    }
    __syncthreads();
    if (threadIdx.x < 128) {
        int c = threadIdx.x;
        float t = 0.f;
#pragma unroll
        for (int w8 = 0; w8 < 8; ++w8) t += dstage[w8][c];
        atomicAdd(&sums[c], t);
    }
}

// ---------------------------------------------------------------------------
// Kernel 3: full-image writer, c-chunked. Block = (y row, 16-c chunk).
// Each lane loads its winner's 64B y_buf chunk line ONCE (4x float4), then
// reuses it across the 16 channels. All stores coalesced.
// ---------------------------------------------------------------------------
__global__ __launch_bounds__(256) void write_k(
    const float* __restrict__ y_buf,   // [N, 64] pre-BN
    const float* __restrict__ sums,    // [128]
    const float* __restrict__ gamma,   // [64]
    const float* __restrict__ beta,    // [64]
    const int*   __restrict__ winner,  // [256*256]
    float* __restrict__ out)           // [64, 256, 1216]
{
    const int y  = blockIdx.x >> 2;
    const int ch = (blockIdx.x & 3) * 16;
    const int t  = threadIdx.x;
    const float inv_n = 1.f / (float)NPTS;

    const int wn = winner[y * PIXR + t];       // coalesced 1KB, kept in VGPR
    float4 yl[4] = {{0,0,0,0},{0,0,0,0},{0,0,0,0},{0,0,0,0}};
    if (wn >= 0) {
        const float4* yp = (const float4*)(y_buf + wn * 64 + ch);  // 64B line
        yl[0] = yp[0]; yl[1] = yp[1]; yl[2] = yp[2]; yl[3] = yp[3];
    }
    const float* ylf = (const float*)yl;

#pragma unroll
    for (int cc = 0; cc < 16; ++cc) {
        int c = ch + cc;
        float mean = sums[c] * inv_n;
        float var  = sums[64 + c] * inv_n - mean * mean;
        float rstd = rsqrtf(var + EPSF);
        float A = gamma[c] * rstd;
        float B = beta[c] - mean * A;

        float v = (wn >= 0) ? fmaxf(fmaf(A, ylf[cc], B), 0.f) : 0.f;
        float* row = out + c * HWC + y * WDIM;
        row[t] = v;                            // coalesced 1KB
        if (t < 240) {
            float4 z = {0.f, 0.f, 0.f, 0.f};
            ((float4*)(row + 256))[t] = z;     // zero x = 256..1215
        }
    }
}

// ---------------------------------------------------------------------------
extern "C" void kernel_launch(void* const* d_in, const int* in_sizes, int n_in,
                              void* d_out, int out_size, void* d_ws, size_t ws_size,
                              hipStream_t stream) {
    const float* feat   = (const float*)d_in[0];   // [1,64,256,1216]
    const float* diff   = (const float*)d_in[1];   // [1,40000,9,3]
    const int*   pix    = (const int*)  d_in[2];   // [1,40000,2]
    const int*   nnpix  = (const int*)  d_in[3];   // [1,40000,9,2]
    const float* W1     = (const float*)d_in[4];   // [3,32]
    const float* b1v    = (const float*)d_in[5];   // [32]
    const float* W2     = (const float*)d_in[6];   // [32,64]
    const float* b2v    = (const float*)d_in[7];   // [64]
    const float* conv_w = (const float*)d_in[8];   // [64,64]
    const float* conv_b = (const float*)d_in[9];   // [64]
    const float* gamma  = (const float*)d_in[10];  // [64]
    const float* beta   = (const float*)d_in[11];  // [64]
    float* out = (float*)d_out;

    // workspace layout (bytes):
    //   feat_t : 0        .. 8388608     (256*256*64 fp16)
    //   y_buf  : 8388608  .. 18628608    (40000*64 f32)
    //   sums   : 18628608 .. 18629120    (128 f32)
    //   winner : 18629120 .. 18891264    (256*256 i32)
    char* ws = (char*)d_ws;
    unsigned short* feat_t = (unsigned short*)(ws);
    float* y_buf   = (float*)(ws + 8388608);
    float* sums    = (float*)(ws + 18628608);
    int*   winner  = (int*)  (ws + 18629120);

    prep_k<<<1024, 256, 0, stream>>>(feat, feat_t, winner, sums);
    point_k<<<625, 512, 0, stream>>>(feat_t, diff, nnpix, pix, W1, b1v, W2, b2v,
                                     conv_w, conv_b, winner, y_buf, sums);
    write_k<<<1024, 256, 0, stream>>>(y_buf, sums, gamma, beta, winner, out);
}

// Round 7
// 197.517 us; speedup vs baseline: 1.0777x; 1.0777x over previous
//
#include <hip/hip_runtime.h>
#include <hip/hip_fp16.h>

// Problem constants
#define HDIM 256
#define WDIM 1216
#define HWC  (HDIM*WDIM)     // 311296
#define NPTS 40000
#define KNN  9
#define PIXR 256             // index range of pixel coords (0..255)
#define EPSF 1e-5f

typedef __attribute__((ext_vector_type(8))) short bf16x8;
typedef __attribute__((ext_vector_type(4))) float f32x4;

static __device__ __forceinline__ unsigned short f2bf(float f) {
    unsigned int u = __float_as_uint(f);
    u += 0x7FFFu + ((u >> 16) & 1u);     // round-nearest-even
    return (unsigned short)(u >> 16);
}

static __device__ __forceinline__ float h2f(unsigned short u) {
    __half h = __builtin_bit_cast(__half, u);
    return __half2float(h);
}

// ---------------------------------------------------------------------------
// Kernel 1: prep — feature transpose to fp16 [pix][chan] (1024 blocks) +
// workspace init side-jobs (winner=-1, sums=0). Stream order guarantees init
// before point_k. fp16 feat_t (validated R14): halves gather footprint
// (8.4MB image -> better per-XCD L2 retention), FETCH 40.7->20.7MB,
// absmax unchanged at 0.03125.
// ---------------------------------------------------------------------------
__global__ __launch_bounds__(256) void prep_k(const float* __restrict__ feat,
                                              unsigned short* __restrict__ feat_t,
                                              int* __restrict__ winner,
                                              float* __restrict__ sums) {
    __shared__ float tile[64][65];
    const int iy   = blockIdx.x >> 2;
    const int ixb  = (blockIdx.x & 3) * 64;
    const int lane = threadIdx.x & 63;
    const int w    = threadIdx.x >> 6;

    const int tid = blockIdx.x * 256 + threadIdx.x;
    if (tid < PIXR * PIXR) winner[tid] = -1;
    if (tid < 128) sums[tid] = 0.f;

#pragma unroll
    for (int r = 0; r < 16; ++r) {
        int cc = w * 16 + r;
        tile[cc][lane] = feat[cc * HWC + iy * WDIM + ixb + lane];   // 256B coalesced
    }
    __syncthreads();
#pragma unroll
    for (int r = 0; r < 16; ++r) {
        int ix = w * 16 + r;
        unsigned short hv = __builtin_bit_cast(unsigned short,
                                               __float2half_rn(tile[lane][ix]));
        feat_t[(iy * PIXR + ixb + ix) * 64 + lane] = hv;  // 128B/wave coalesced
    }
}

// ---------------------------------------------------------------------------
// Kernel 2: MFMA point kernel. R15.
// R14 post-mortem: fp16 halved FETCH (40.7->20.7MB, prediction matched) but
// dur regressed 47->58.7us because h2f AT THE FILL SITE made the issue
// depend on the load data -> compiler emitted vmcnt(0) at ISSUE ->
// the 2-deep prefetch collapsed into a synchronous gather.
// Fix: pipeline buffers hold RAW ushort4 bits (2 VGPR/neighbor, issue site
// is pure load -> regs, loads stay in flight); h2f moved to CONSUME (phase
// B top, after the natural counted-vmcnt wait). fp16 zero bits == 0.0f so
// the k>=9 zeroing still works on raw bits.
// Kept (validated): 2-deep named buffers, (512,2) VGPR budget (R2/R3: 2nd
// arg is waves/EU floor *2 for 512-thr; (512,6)=spill disaster, (512,2)
// clean), shfl quad-reduce, row-id npx, 39.9KB LDS, c=4*col+m remap.
// ---------------------------------------------------------------------------
__global__ __launch_bounds__(512, 2) void point_k(
    const unsigned short* __restrict__ feat_t, // [256*256, 64] fp16
    const float* __restrict__ diff,     // [N, 9, 3]
    const int*   __restrict__ nnpix,    // [N, 9, 2]
    const int*   __restrict__ pix,      // [N, 2]
    const float* __restrict__ W1,       // [3, 32]
    const float* __restrict__ b1,       // [32]
    const float* __restrict__ W2,       // [32, 64]
    const float* __restrict__ b2,       // [64]
    const float* __restrict__ conv_w,   // [64, 64] (out, in)
    const float* __restrict__ conv_b,   // [64]
    int*   __restrict__ winner,         // [256*256]
    float* __restrict__ y_buf,          // [N, 64]
    float* __restrict__ sums)           // [128]
{
    __shared__ float dstage[8][224];          // diff (216 used); reused for BN staging
    __shared__ int   npx[8][96];              // row-ids, 12/point (9 used), per wave
    __shared__ unsigned int hl[8][2][320];    // hmid, double-buffered, 80B row stride
    __shared__ unsigned short msgst[8][576];  // msg [8 pts][72 u16] per wave
    // total: 7168 + 3072 + 20480 + 9216 = 39936 B

    const int l   = threadIdx.x & 63;
    const int w   = __builtin_amdgcn_readfirstlane(threadIdx.x >> 6);
    const int q   = l >> 4;
    const int col = l & 15;
    const int nbase = blockIdx.x * 64 + w * 8;    // wave's 8 points

    // winner side-job: one thread per point of this block (64 points)
    if (threadIdx.x < 64) {
        int n = blockIdx.x * 64 + threadIdx.x;
        int px = pix[2 * n];
        int py = pix[2 * n + 1];
        atomicMax(&winner[py * PIXR + px], n);
    }

    // ---- persistent fragments for the g-loop ----
    // W2 B-frag under the channel remap: B[j = 8q+t][n=col] holds c = 4*col+m.
    bf16x8 bw2[4];
#pragma unroll
    for (int t = 0; t < 8; ++t) {
        float4 v = ((const float4*)W2)[(q * 8 + t) * 16 + col];
        bw2[0][t] = (short)f2bf(v.x);
        bw2[1][t] = (short)f2bf(v.y);
        bw2[2][t] = (short)f2bf(v.z);
        bw2[3][t] = (short)f2bf(v.w);
    }
    float b2m[4];
    {
        float4 bv = ((const float4*)b2)[col];
        b2m[0] = bv.x; b2m[1] = bv.y; b2m[2] = bv.z; b2m[3] = bv.w;
    }

    // W1 columns for phase A (j0 = 2*col, j0+1)
    const int j0 = 2 * col;
    const float wa0 = W1[j0],     wa1 = W1[32 + j0],     wa2 = W1[64 + j0],     ba = b1[j0];
    const float wb0 = W1[j0 + 1], wb1 = W1[32 + j0 + 1], wb2 = W1[64 + j0 + 1], bb = b1[j0 + 1];

    // preload diff (216 f32) for the wave's 8 points
#pragma unroll
    for (int t = 0; t < 4; ++t) { int idx = l + 64 * t; if (idx < 216) dstage[w][idx] = diff[nbase * 27 + idx]; }
    // preload nnpix as precomputed row-ids, 12-padded per point (96 ints)
#pragma unroll
    for (int t = 0; t < 2; ++t) {
        int idx = l + 64 * t;
        if (idx < 96) {
            int point = idx / 12;
            int k     = idx - point * 12;
            int rid = 0;
            if (k < 9) {
                int2 pp = *(const int2*)(nnpix + (nbase + point) * 18 + 2 * k);
                rid = pp.y * PIXR + pp.x;
            }
            npx[w][idx] = rid;
        }
    }

    // zero hmid pad rows 9..15 in BOTH buffers
    for (int z = 180 + l; z < 320; z += 64) { hl[w][0][z] = 0; hl[w][1][z] = 0; }

    // gather pipeline buffers — RAW fp16 bits, named, statically indexed only
    ushort4 fvc_r[4], fvn_r[4], fv2_r[4];   // [neighbor i], lane covers c=4*col+m

// issue the 4 neighbor-row gathers for point gg into named raw buffer `buf`
// pure load -> regs at the issue site: NO dependent ALU, loads stay in flight
#define ISSUE_INTO(buf, gg)                                                     \
    {                                                                           \
        int4 r4 = *(const int4*)&npx[w][(gg) * 12 + q * 4];                     \
        int rid[4] = {r4.x, r4.y, r4.z, r4.w};                                  \
        _Pragma("unroll")                                                       \
        for (int i = 0; i < 4; ++i) {                                           \
            int k = q * 4 + i;                                                  \
            buf[i] = (ushort4){0, 0, 0, 0};                                     \
            if (k < 9)                                                          \
                buf[i] = *(const ushort4*)(feat_t + rid[i] * 64 + 4 * col);     \
        }                                                                       \
    }

// MLP layer 1 for point gg -> hl[(gg)&1]
#define PHASE_A(gg)                                                             \
    {                                                                           \
        unsigned int* hln = hl[w][(gg) & 1];                                    \
        _Pragma("unroll")                                                       \
        for (int i2 = 0; i2 < 3; ++i2) {                                        \
            int k2 = q + 4 * i2;                                                \
            if (k2 < 9) {                                                       \
                float d0 = dstage[w][(gg) * 27 + k2 * 3];                       \
                float d1 = dstage[w][(gg) * 27 + k2 * 3 + 1];                   \
                float d2 = dstage[w][(gg) * 27 + k2 * 3 + 2];                   \
                float h0 = fmaxf(fmaf(d0, wa0, fmaf(d1, wa1, fmaf(d2, wa2, ba))), 0.f); \
                float h1 = fmaxf(fmaf(d0, wb0, fmaf(d1, wb1, fmaf(d2, wb2, bb))), 0.f); \
                hln[k2 * 20 + col] = (unsigned int)f2bf(h0) | ((unsigned int)f2bf(h1) << 16); \
            }                                                                   \
        }                                                                       \
    }

    // zero-init fv2_r (read by rotation before first conditional issue paths)
#pragma unroll
    for (int i = 0; i < 4; ++i) fv2_r[i] = (ushort4){0, 0, 0, 0};

    // ---- pipeline prologue: gathers for g=0 and g=1, phase A for g=0 ----
    ISSUE_INTO(fvc_r, 0);
    ISSUE_INTO(fvn_r, 1);
    PHASE_A(0);

    for (int g = 0; g < 8; ++g) {
        // --- issue gathers 2 ahead, phase A 1 ahead ---
        if (g < 6) ISSUE_INTO(fv2_r, g + 2);
        if (g < 7) PHASE_A(g + 1);           // writes hl[(g+1)&1], != hl[g&1]

        // --- phase B(g): convert fvc_r at CONSUME, wts via MFMA, weighted sum ---
        float fcv[4][4];                     // [neighbor i][m]
#pragma unroll
        for (int i = 0; i < 4; ++i) {
            fcv[i][0] = h2f(fvc_r[i].x); fcv[i][1] = h2f(fvc_r[i].y);
            fcv[i][2] = h2f(fvc_r[i].z); fcv[i][3] = h2f(fvc_r[i].w);
        }
        bf16x8 a;
        {
            uint4 av = *(const uint4*)((const char*)hl[w][g & 1] + col * 80 + q * 16);
            a = __builtin_bit_cast(bf16x8, av);
        }
        float pm[4];
#pragma unroll
        for (int m = 0; m < 4; ++m) {
            f32x4 acc = {b2m[m], b2m[m], b2m[m], b2m[m]};
            acc = __builtin_amdgcn_mfma_f32_16x16x32_bf16(a, bw2[m], acc, 0, 0, 0);
            float p = 0.f;
#pragma unroll
            for (int i = 0; i < 4; ++i)
                p = fmaf(fmaxf(acc[i], 0.f), fcv[i][m], p);
            p += __shfl_xor(p, 16);
            p += __shfl_xor(p, 32);
            pm[m] = p;
        }
        if (q == 0) {
            ushort4 ms;
            ms.x = f2bf(pm[0]); ms.y = f2bf(pm[1]);
            ms.z = f2bf(pm[2]); ms.w = f2bf(pm[3]);
            *(ushort4*)(&msgst[w][g * 72 + 4 * col]) = ms;   // c = 4*col+m, 8B
        }

        // rotate pipeline registers: fvc_r <- fvn_r <- fv2_r (raw 8B movs)
#pragma unroll
        for (int i = 0; i < 4; ++i) { fvc_r[i] = fvn_r[i]; fvn_r[i] = fv2_r[i]; }
    }
#undef ISSUE_INTO
#undef PHASE_A

    // ---- phase C: batched 1x1 conv over the wave's 8 points ----
    // D rows 0..7 are the valid points (quads 0,1); rows 8..15 are discarded
    // duplicates (A-frag row col&7), so quads 2,3 skip stores/BN.
    bf16x8 bcv[4][2];
#pragma unroll
    for (int m = 0; m < 4; ++m)
#pragma unroll
        for (int h = 0; h < 2; ++h) {
            float4 v0 = ((const float4*)conv_w)[(col + 16 * m) * 16 + h * 8 + q * 2];
            float4 v1 = ((const float4*)conv_w)[(col + 16 * m) * 16 + h * 8 + q * 2 + 1];
            bcv[m][h][0] = (short)f2bf(v0.x); bcv[m][h][1] = (short)f2bf(v0.y);
            bcv[m][h][2] = (short)f2bf(v0.z); bcv[m][h][3] = (short)f2bf(v0.w);
            bcv[m][h][4] = (short)f2bf(v1.x); bcv[m][h][5] = (short)f2bf(v1.y);
            bcv[m][h][6] = (short)f2bf(v1.z); bcv[m][h][7] = (short)f2bf(v1.w);
        }
    float cbm[4];
#pragma unroll
    for (int m = 0; m < 4; ++m) cbm[m] = conv_b[col + 16 * m];

    float s1[4] = {0.f, 0.f, 0.f, 0.f}, s2[4] = {0.f, 0.f, 0.f, 0.f};

    bf16x8 am[2];
    const int crow = col & 7;
#pragma unroll
    for (int h = 0; h < 2; ++h) {
        uint4 av = *(const uint4*)((const char*)msgst[w] + crow * 144 + h * 64 + q * 16);
        am[h] = __builtin_bit_cast(bf16x8, av);
    }
#pragma unroll
    for (int m = 0; m < 4; ++m) {
        f32x4 acc = {cbm[m], cbm[m], cbm[m], cbm[m]};
        acc = __builtin_amdgcn_mfma_f32_16x16x32_bf16(am[0], bcv[m][0], acc, 0, 0, 0);
        acc = __builtin_amdgcn_mfma_f32_16x16x32_bf16(am[1], bcv[m][1], acc, 0, 0, 0);
        if (q < 2) {
#pragma unroll
            for (int i = 0; i < 4; ++i) {
                float y = acc[i];                    // row n_local = 4q+i, col c
                y_buf[(nbase + q * 4 + i) * 64 + col + 16 * m] = y;
                s1[m] += y;
                s2[m] = fmaf(y, y, s2[m]);
            }
        }
    }

    // ---- BN partials: cross-quad shfl reduce -> per-wave staging in dstage
    //      (dead after g-loop) -> one block-level reduction -> 128 atomics ----
#pragma unroll
    for (int m = 0; m < 4; ++m) {
        float a1 = s1[m], a2 = s2[m];
        a1 += __shfl_xor(a1, 16); a1 += __shfl_xor(a1, 32);
        a2 += __shfl_xor(a2, 16); a2 += __shfl_xor(a2, 32);
        if (q == 0) {
            dstage[w][col + 16 * m]      = a1;
            dstage[w][64 + col + 16 * m] = a2;
        }
    }
    __syncthreads();
    if (threadIdx.x < 128) {
        int c = threadIdx.x;
        float t = 0.f;
#pragma unroll
        for (int w8 = 0; w8 < 8; ++w8) t += dstage[w8][c];
        atomicAdd(&sums[c], t);
    }
}

// ---------------------------------------------------------------------------
// Kernel 3: full-image writer, c-chunked. Block = (y row, 16-c chunk).
// Each lane loads its winner's 64B y_buf chunk line ONCE (4x float4), then
// reuses it across the 16 channels. All stores coalesced.
// ---------------------------------------------------------------------------
__global__ __launch_bounds__(256) void write_k(
    const float* __restrict__ y_buf,   // [N, 64] pre-BN
    const float* __restrict__ sums,    // [128]
    const float* __restrict__ gamma,   // [64]
    const float* __restrict__ beta,    // [64]
    const int*   __restrict__ winner,  // [256*256]
    float* __restrict__ out)           // [64, 256, 1216]
{
    const int y  = blockIdx.x >> 2;
    const int ch = (blockIdx.x & 3) * 16;
    const int t  = threadIdx.x;
    const float inv_n = 1.f / (float)NPTS;

    const int wn = winner[y * PIXR + t];       // coalesced 1KB, kept in VGPR
    float4 yl[4] = {{0,0,0,0},{0,0,0,0},{0,0,0,0},{0,0,0,0}};
    if (wn >= 0) {
        const float4* yp = (const float4*)(y_buf + wn * 64 + ch);  // 64B line
        yl[0] = yp[0]; yl[1] = yp[1]; yl[2] = yp[2]; yl[3] = yp[3];
    }
    const float* ylf = (const float*)yl;

#pragma unroll
    for (int cc = 0; cc < 16; ++cc) {
        int c = ch + cc;
        float mean = sums[c] * inv_n;
        float var  = sums[64 + c] * inv_n - mean * mean;
        float rstd = rsqrtf(var + EPSF);
        float A = gamma[c] * rstd;
        float B = beta[c] - mean * A;

        float v = (wn >= 0) ? fmaxf(fmaf(A, ylf[cc], B), 0.f) : 0.f;
        float* row = out + c * HWC + y * WDIM;
        row[t] = v;                            // coalesced 1KB
        if (t < 240) {
            float4 z = {0.f, 0.f, 0.f, 0.f};
            ((float4*)(row + 256))[t] = z;     // zero x = 256..1215
        }
    }
}

// ---------------------------------------------------------------------------
extern "C" void kernel_launch(void* const* d_in, const int* in_sizes, int n_in,
                              void* d_out, int out_size, void* d_ws, size_t ws_size,
                              hipStream_t stream) {
    const float* feat   = (const float*)d_in[0];   // [1,64,256,1216]
    const float* diff   = (const float*)d_in[1];   // [1,40000,9,3]
    const int*   pix    = (const int*)  d_in[2];   // [1,40000,2]
    const int*   nnpix  = (const int*)  d_in[3];   // [1,40000,9,2]
    const float* W1     = (const float*)d_in[4];   // [3,32]
    const float* b1v    = (const float*)d_in[5];   // [32]
    const float* W2     = (const float*)d_in[6];   // [32,64]
    const float* b2v    = (const float*)d_in[7];   // [64]
    const float* conv_w = (const float*)d_in[8];   // [64,64]
    const float* conv_b = (const float*)d_in[9];   // [64]
    const float* gamma  = (const float*)d_in[10];  // [64]
    const float* beta   = (const float*)d_in[11];  // [64]
    float* out = (float*)d_out;

    // workspace layout (bytes):
    //   feat_t : 0        .. 8388608     (256*256*64 fp16)
    //   y_buf  : 8388608  .. 18628608    (40000*64 f32)
    //   sums   : 18628608 .. 18629120    (128 f32)
    //   winner : 18629120 .. 18891264    (256*256 i32)
    char* ws = (char*)d_ws;
    unsigned short* feat_t = (unsigned short*)(ws);
    float* y_buf   = (float*)(ws + 8388608);
    float* sums    = (float*)(ws + 18628608);
    int*   winner  = (int*)  (ws + 18629120);

    prep_k<<<1024, 256, 0, stream>>>(feat, feat_t, winner, sums);
    point_k<<<625, 512, 0, stream>>>(feat_t, diff, nnpix, pix, W1, b1v, W2, b2v,
                                     conv_w, conv_b, winner, y_buf, sums);
    write_k<<<1024, 256, 0, stream>>>(y_buf, sums, gamma, beta, winner, out);
}